// Round 11
// baseline (3170.142 us; speedup 1.0000x reference)
//
#include <hip/hip_runtime.h>
#include <hip/hip_fp16.h>

// Bidirectional GRU, b=32, t=2048, in=hid=256, gate order r,z,n.
// gx = x@W_ih^T + b_ih (+b_hr,b_hz folded) precomputed fp16 in d_ws.
// Recurrence: 64 WGs (batch x dir), 768 threads = 12 waves = 4 k-seg x 3
// row-groups, 128 packed-fp16 W regs per lane.
// R11: dot phase via v_pk_fma_f16 (fp16x2 accumulate) instead of
// v_dot2_f32_f16. Measured dot2 ~4cyc/wave64 (f32-accum -> fp32-pipe
// rate); packed fp16 FMA should be 2cyc (CDNA vector fp16 = 2x fp32).
// Two 16-deep sub-chains per row bound fp16 rounding (~1.4e-3/gh);
// final sums + b_hn combine in fp32.

typedef __fp16 half2_t __attribute__((ext_vector_type(2)));

static constexpr int T_STEPS = 2048;
static constexpr int BATCH   = 32;
static constexpr int HID     = 256;
static constexpr int IN      = 256;
static constexpr int G3      = 768;   // 3*HID

__device__ __forceinline__ float fdot2(half2_t a, half2_t b, float c) {
    return __builtin_amdgcn_fdot2(a, b, c, false);
}

// __syncthreads() drains vmcnt(0) (store acks + prefetch) -- we only need
// LDS ordering, so wait lgkmcnt(0) and barrier.
__device__ __forceinline__ void barrier_lgkm() {
    asm volatile("s_waitcnt lgkmcnt(0)\n\ts_barrier" ::: "memory");
}

// ---------------------------------------------------------------------------
// Kernel 1: gx[m][j] = sum_k x[m][k]*W_ih[j][k] + b_ih[j] (+ b_hh[j] for the
// r,z thirds). Stored fp16.
// ---------------------------------------------------------------------------
__global__ __launch_bounds__(256, 2) void gx_gemm(
        const float* __restrict__ x,
        const float* __restrict__ Wih,
        const float* __restrict__ bih,
        const float* __restrict__ bhh,
        _Float16* __restrict__ gx) {
    __shared__ ushort As[64 * 256];   // 32KB
    __shared__ ushort Bs[64 * 256];   // 32KB

    const int tid = threadIdx.x;
    const int m0  = blockIdx.x * 64;
    const int tx  = tid & 15;         // n-dim
    const int ty  = tid >> 4;         // m-dim

    // ---- stage A tile (x): 64 rows x 256 cols ----
#pragma unroll
    for (int i = 0; i < 16; ++i) {
        int f    = tid + 256 * i;
        int row  = f >> 6;
        int col4 = f & 63;
        float4 v = *(const float4*)(x + (size_t)(m0 + row) * IN + col4 * 4);
        half2_t h0 = __builtin_amdgcn_cvt_pkrtz(v.x, v.y);
        half2_t h1 = __builtin_amdgcn_cvt_pkrtz(v.z, v.w);
        int chunk = col4 >> 1;
        int idx = row * 256 + ((chunk ^ (row & 7)) * 8) + (col4 & 1) * 4;
        uint2 wv;
        wv.x = __builtin_bit_cast(unsigned, h0);
        wv.y = __builtin_bit_cast(unsigned, h1);
        *(uint2*)(As + idx) = wv;
    }

    for (int nb = 0; nb < 12; ++nb) {
#pragma unroll
        for (int i = 0; i < 16; ++i) {
            int f    = tid + 256 * i;
            int row  = f >> 6;
            int col4 = f & 63;
            float4 v = *(const float4*)(Wih + (size_t)(nb * 64 + row) * IN + col4 * 4);
            half2_t h0 = __builtin_amdgcn_cvt_pkrtz(v.x, v.y);
            half2_t h1 = __builtin_amdgcn_cvt_pkrtz(v.z, v.w);
            int chunk = col4 >> 1;
            int idx = row * 256 + ((chunk ^ (row & 7)) * 8) + (col4 & 1) * 4;
            uint2 wv;
            wv.x = __builtin_bit_cast(unsigned, h0);
            wv.y = __builtin_bit_cast(unsigned, h1);
            *(uint2*)(Bs + idx) = wv;
        }
        barrier_lgkm();

        float acc[4][4];
#pragma unroll
        for (int jm = 0; jm < 4; ++jm)
#pragma unroll
            for (int jn = 0; jn < 4; ++jn) acc[jm][jn] = 0.f;

#pragma unroll 4
        for (int kc = 0; kc < 32; ++kc) {
            union { uint4 u; half2_t h[4]; } av[4], bv[4];
#pragma unroll
            for (int jm = 0; jm < 4; ++jm) {
                int r = ty * 4 + jm;
                av[jm].u = *(const uint4*)(As + r * 256 + ((kc ^ (r & 7)) * 8));
            }
#pragma unroll
            for (int jn = 0; jn < 4; ++jn) {
                int r = tx + 16 * jn;
                bv[jn].u = *(const uint4*)(Bs + r * 256 + ((kc ^ (r & 7)) * 8));
            }
#pragma unroll
            for (int jm = 0; jm < 4; ++jm)
#pragma unroll
                for (int jn = 0; jn < 4; ++jn)
#pragma unroll
                    for (int p = 0; p < 4; ++p)
                        acc[jm][jn] = fdot2(av[jm].h[p], bv[jn].h[p], acc[jm][jn]);
        }

#pragma unroll
        for (int jn = 0; jn < 4; ++jn) {
            int n = nb * 64 + tx + 16 * jn;
            float bias = bih[n] + (n < 512 ? bhh[n] : 0.f);
#pragma unroll
            for (int jm = 0; jm < 4; ++jm) {
                int m = m0 + ty * 4 + jm;
                gx[(size_t)m * G3 + n] = (_Float16)(acc[jm][jn] + bias);
            }
        }
        barrier_lgkm();   // WAR: Bs restage next iteration
    }
}

// ---------------------------------------------------------------------------
// Kernel 2: recurrence. grid=64 (b,dir), block=768 (12 waves).
// Wave w: k-segment s=w&3 (64 k), row-group g=w>>2 (256 rows).
// Lane: 4 rows x 64 k of W_hh = 128 packed fp16 regs.
// Dot phase: 128 v_pk_fma_f16 per lane (fp16x2 accumulate, 2 sub-chains
// per row), fp32 combine + b_hn fold. 2 lgkm-only barriers/step.
// ---------------------------------------------------------------------------
__attribute__((amdgpu_waves_per_eu(1, 3)))
__global__ __launch_bounds__(768) void gru_seq(
        const _Float16* __restrict__ gx,
        const float* __restrict__ Whh,
        const float* __restrict__ bhh,
        float* __restrict__ out0,     // outputs [32,2048,512]
        float* __restrict__ out1) {   // hiddens [2048,32,512]
    __shared__ float  P[4 * 768];     // 12KB partials
    __shared__ ushort h16[256];       // h as fp16
    __shared__ ushort gxb[768];       // this step's gx row (fp16)

    const int tid = threadIdx.x;
    const int b   = blockIdx.x & 31;
    const int d   = blockIdx.x >> 5;
    const int w   = tid >> 6;
    const int L   = tid & 63;
    const int s   = w & 3;            // k segment
    const int g   = w >> 2;           // row group (0..2)

    // ---- W_hh fragment -> registers as packed fp16 ----
    // Wb folds ONLY b_hn (rows 512..767): r,z biases are already in gx.
    half2_t Wr[4][32];
    float   Wb[4];
#pragma unroll
    for (int jr = 0; jr < 4; ++jr) {
        const int row = g * 256 + jr * 64 + L;
        const float* wrow = Whh + (size_t)row * HID + s * 64;
#pragma unroll
        for (int q = 0; q < 32; ++q) {
            float2 wv = *(const float2*)(wrow + 2 * q);
            Wr[jr][q] = __builtin_amdgcn_cvt_pkrtz(wv.x, wv.y);
        }
        Wb[jr] = (s == 0 && row >= 512) ? bhh[row] : 0.f;
    }

    float hprev = 0.f;
    if (tid < 256) h16[tid] = 0;      // h0 = 0

    const int tp0 = d ? (T_STEPS - 1) : 0;
    const int sgn = d ? -1 : 1;

    const _Float16* gp = gx + ((size_t)b * T_STEPS + tp0) * G3 + tid * 8;
    const int gpd = sgn * G3;
    uint4 greg{};
    if (tid < 96) greg = *(const uint4*)gp;

    float* o0 = out0 + ((size_t)b * T_STEPS + tp0) * 512 + d * 256 + tid;
    float* o1 = out1 + ((size_t)tp0 * BATCH + b) * 512 + d * 256 + tid;
    const int o0d = sgn * 512;
    const int o1d = sgn * (BATCH * 512);

    __syncthreads();

    for (int t = 0; t < T_STEPS; ++t) {
        // land this step's gx row in LDS; issue next step's load (hides HBM
        // latency under dot+gate; lgkm-only barriers keep it in flight)
        if (tid < 96) {
            *(uint4*)(gxb + tid * 8) = greg;
            if (t + 1 < T_STEPS) {
                gp += gpd;
                greg = *(const uint4*)gp;
            }
        }

        // ---- dot phase: 128 v_pk_fma_f16 per lane ----
        // acch[jr][u]: fp16x2 accumulator, 16 pk_fma each (32 products);
        // fp16 partial-sum rounding bounded to ~1.4e-3 per gh element.
        half2_t acch[4][2];
#pragma unroll
        for (int jr = 0; jr < 4; ++jr) {
            acch[jr][0] = half2_t{0, 0};
            acch[jr][1] = half2_t{0, 0};
        }
#pragma unroll
        for (int c = 0; c < 4; ++c) {
            union { uint4 u; half2_t h[4]; } hh0, hh1;
            hh0.u = *(const uint4*)(h16 + s * 64 + c * 16);       // broadcast
            hh1.u = *(const uint4*)(h16 + s * 64 + c * 16 + 8);   // broadcast
#pragma unroll
            for (int jr = 0; jr < 4; ++jr) {
#pragma unroll
                for (int p = 0; p < 4; ++p) {
                    acch[jr][0] = Wr[jr][c * 8 + p]     * hh0.h[p] + acch[jr][0];
                    acch[jr][1] = Wr[jr][c * 8 + 4 + p] * hh1.h[p] + acch[jr][1];
                }
            }
        }
#pragma unroll
        for (int jr = 0; jr < 4; ++jr) {
            float acc = Wb[jr]
                      + ((float)acch[jr][0][0] + (float)acch[jr][0][1])
                      + ((float)acch[jr][1][0] + (float)acch[jr][1][1]);
            P[s * 768 + g * 256 + jr * 64 + L] = acc;
        }

        barrier_lgkm();

        // ---- gate phase (first 4 waves) ----
        if (tid < 256) {
            const int i = tid;
            float hr = (P[i]       + P[768 + i])  + (P[1536 + i] + P[2304 + i]);
            float hz = (P[256 + i] + P[1024 + i]) + (P[1792 + i] + P[2560 + i]);
            float hn = (P[512 + i] + P[1280 + i]) + (P[2048 + i] + P[2816 + i]);
            const _Float16* gxh = (const _Float16*)gxb;
            float xr = (float)gxh[i]       + hr;   // b_ih+b_hr in gx
            float xz = (float)gxh[256 + i] + hz;   // b_ih+b_hz in gx
            // sigmoid via exp2; saturates cleanly at +-inf (no NaN)
            float r = __builtin_amdgcn_rcpf(1.f + __builtin_amdgcn_exp2f(xr * -1.44269504f));
            float z = __builtin_amdgcn_rcpf(1.f + __builtin_amdgcn_exp2f(xz * -1.44269504f));
            float nx = (float)gxh[512 + i] + r * hn;   // hn includes b_hn
            float e2 = __builtin_amdgcn_exp2f(nx * 2.88539008f);
            float n  = 1.f - 2.f * __builtin_amdgcn_rcpf(1.f + e2);   // tanh
            float h  = n + z * (hprev - n);
            hprev = h;

            h16[i] = __builtin_bit_cast(ushort, (_Float16)h);
            *o0 = h; *o1 = h;
            o0 += o0d; o1 += o1d;
        }
        barrier_lgkm();
    }
}

// ---------------------------------------------------------------------------
extern "C" void kernel_launch(void* const* d_in, const int* in_sizes, int n_in,
                              void* d_out, int out_size, void* d_ws, size_t ws_size,
                              hipStream_t stream) {
    const float* x   = (const float*)d_in[0];
    const float* Wih = (const float*)d_in[1];
    const float* Whh = (const float*)d_in[2];
    const float* bih = (const float*)d_in[3];
    const float* bhh = (const float*)d_in[4];

    float* out0 = (float*)d_out;                          // outputs [32,2048,512]
    float* out1 = out0 + (size_t)BATCH * T_STEPS * 512;   // hiddens [2048,32,512]

    _Float16* gx = (_Float16*)d_ws;                       // 96MB

    gx_gemm<<<dim3(65536 / 64), dim3(256), 0, stream>>>(x, Wih, bih, bhh, gx);
    gru_seq<<<dim3(BATCH * 2), dim3(768), 0, stream>>>(gx, Whh, bhh, out0, out1);
}

// Round 12
// 2804.276 us; speedup vs baseline: 1.1305x; 1.1305x over previous
//
#include <hip/hip_runtime.h>
#include <hip/hip_fp16.h>

// Bidirectional GRU, b=32, t=2048, in=hid=256, gate order r,z,n.
// gx = x@W_ih^T + b_ih (+b_hr,b_hz folded) precomputed fp16 in d_ws.
// R12: back to v_dot2 (R11 proved pk_fma is no faster and adds combine
// overhead). Full-K row layout: lane = 1 row x K=256 (128 dot2 in 4
// independent 32-deep chains) -> writes FINAL gh[row]; kills the 4-way
// partial sum (gate 12 reads -> 3), partial writes 4 -> 1, b_hn folded
// into chain-0 init. gx prefetch moved off the gate waves (to waves 8-9).
// Step model: 1536 dot-issue + ~200 gate + ~700 sync =~2450 cyc.

typedef __fp16 half2_t __attribute__((ext_vector_type(2)));

static constexpr int T_STEPS = 2048;
static constexpr int BATCH   = 32;
static constexpr int HID     = 256;
static constexpr int IN      = 256;
static constexpr int G3      = 768;   // 3*HID

__device__ __forceinline__ float fdot2(half2_t a, half2_t b, float c) {
    return __builtin_amdgcn_fdot2(a, b, c, false);
}

// __syncthreads() drains vmcnt(0) (store acks + prefetch) -- we only need
// LDS ordering, so wait lgkmcnt(0) and barrier.
__device__ __forceinline__ void barrier_lgkm() {
    asm volatile("s_waitcnt lgkmcnt(0)\n\ts_barrier" ::: "memory");
}

// ---------------------------------------------------------------------------
// Kernel 1: gx[m][j] = sum_k x[m][k]*W_ih[j][k] + b_ih[j] (+ b_hh[j] for the
// r,z thirds). Stored fp16.
// ---------------------------------------------------------------------------
__global__ __launch_bounds__(256, 2) void gx_gemm(
        const float* __restrict__ x,
        const float* __restrict__ Wih,
        const float* __restrict__ bih,
        const float* __restrict__ bhh,
        _Float16* __restrict__ gx) {
    __shared__ ushort As[64 * 256];   // 32KB
    __shared__ ushort Bs[64 * 256];   // 32KB

    const int tid = threadIdx.x;
    const int m0  = blockIdx.x * 64;
    const int tx  = tid & 15;         // n-dim
    const int ty  = tid >> 4;         // m-dim

    // ---- stage A tile (x): 64 rows x 256 cols ----
#pragma unroll
    for (int i = 0; i < 16; ++i) {
        int f    = tid + 256 * i;
        int row  = f >> 6;
        int col4 = f & 63;
        float4 v = *(const float4*)(x + (size_t)(m0 + row) * IN + col4 * 4);
        half2_t h0 = __builtin_amdgcn_cvt_pkrtz(v.x, v.y);
        half2_t h1 = __builtin_amdgcn_cvt_pkrtz(v.z, v.w);
        int chunk = col4 >> 1;
        int idx = row * 256 + ((chunk ^ (row & 7)) * 8) + (col4 & 1) * 4;
        uint2 wv;
        wv.x = __builtin_bit_cast(unsigned, h0);
        wv.y = __builtin_bit_cast(unsigned, h1);
        *(uint2*)(As + idx) = wv;
    }

    for (int nb = 0; nb < 12; ++nb) {
#pragma unroll
        for (int i = 0; i < 16; ++i) {
            int f    = tid + 256 * i;
            int row  = f >> 6;
            int col4 = f & 63;
            float4 v = *(const float4*)(Wih + (size_t)(nb * 64 + row) * IN + col4 * 4);
            half2_t h0 = __builtin_amdgcn_cvt_pkrtz(v.x, v.y);
            half2_t h1 = __builtin_amdgcn_cvt_pkrtz(v.z, v.w);
            int chunk = col4 >> 1;
            int idx = row * 256 + ((chunk ^ (row & 7)) * 8) + (col4 & 1) * 4;
            uint2 wv;
            wv.x = __builtin_bit_cast(unsigned, h0);
            wv.y = __builtin_bit_cast(unsigned, h1);
            *(uint2*)(Bs + idx) = wv;
        }
        barrier_lgkm();

        float acc[4][4];
#pragma unroll
        for (int jm = 0; jm < 4; ++jm)
#pragma unroll
            for (int jn = 0; jn < 4; ++jn) acc[jm][jn] = 0.f;

#pragma unroll 4
        for (int kc = 0; kc < 32; ++kc) {
            union { uint4 u; half2_t h[4]; } av[4], bv[4];
#pragma unroll
            for (int jm = 0; jm < 4; ++jm) {
                int r = ty * 4 + jm;
                av[jm].u = *(const uint4*)(As + r * 256 + ((kc ^ (r & 7)) * 8));
            }
#pragma unroll
            for (int jn = 0; jn < 4; ++jn) {
                int r = tx + 16 * jn;
                bv[jn].u = *(const uint4*)(Bs + r * 256 + ((kc ^ (r & 7)) * 8));
            }
#pragma unroll
            for (int jm = 0; jm < 4; ++jm)
#pragma unroll
                for (int jn = 0; jn < 4; ++jn)
#pragma unroll
                    for (int p = 0; p < 4; ++p)
                        acc[jm][jn] = fdot2(av[jm].h[p], bv[jn].h[p], acc[jm][jn]);
        }

#pragma unroll
        for (int jn = 0; jn < 4; ++jn) {
            int n = nb * 64 + tx + 16 * jn;
            float bias = bih[n] + (n < 512 ? bhh[n] : 0.f);
#pragma unroll
            for (int jm = 0; jm < 4; ++jm) {
                int m = m0 + ty * 4 + jm;
                gx[(size_t)m * G3 + n] = (_Float16)(acc[jm][jn] + bias);
            }
        }
        barrier_lgkm();   // WAR: Bs restage next iteration
    }
}

// ---------------------------------------------------------------------------
// Kernel 2: recurrence. grid=64 (b,dir), block=768 (12 waves).
// Lane = row (0..767), full K=256: 128 dot2 in 4 independent 32-deep
// chains -> final gh[row] (no partial sums). b_hn (rows>=512) folded into
// chain-0 init. Gate on tid<256: 3 gh reads + gx + 3 transcendentals.
// gx prefetch on waves 8-9. 2 lgkm-only barriers/step.
// ---------------------------------------------------------------------------
__attribute__((amdgpu_waves_per_eu(1, 3)))
__global__ __launch_bounds__(768) void gru_seq(
        const _Float16* __restrict__ gx,
        const float* __restrict__ Whh,
        const float* __restrict__ bhh,
        float* __restrict__ out0,     // outputs [32,2048,512]
        float* __restrict__ out1) {   // hiddens [2048,32,512]
    __shared__ float  gh[768];        // final gh per row
    __shared__ ushort h16[256];       // h as fp16
    __shared__ ushort gxb[768];       // this step's gx row (fp16)

    const int tid = threadIdx.x;
    const int b   = blockIdx.x & 31;
    const int d   = blockIdx.x >> 5;
    const int row = tid;              // 0..767

    // ---- W_hh row -> 128 packed fp16 regs; b_hn folded for n-rows ----
    half2_t Wr[128];
    {
        const float* wrow = Whh + (size_t)row * HID;
#pragma unroll
        for (int q = 0; q < 128; ++q) {
            float2 wv = *(const float2*)(wrow + 2 * q);
            Wr[q] = __builtin_amdgcn_cvt_pkrtz(wv.x, wv.y);
        }
    }
    const float Wb = (row >= 512) ? bhh[row] : 0.f;

    float hprev = 0.f;
    if (tid < 256) h16[tid] = 0;      // h0 = 0

    const int tp0 = d ? (T_STEPS - 1) : 0;
    const int sgn = d ? -1 : 1;

    // gx prefetch on waves 8-9 (threads 512..607)
    const int pt = tid - 512;
    const bool pf = (unsigned)pt < 96u;
    const _Float16* gp = gx + ((size_t)b * T_STEPS + tp0) * G3 + (pf ? pt * 8 : 0);
    const int gpd = sgn * G3;
    uint4 greg{};
    if (pf) greg = *(const uint4*)gp;

    float* o0 = out0 + ((size_t)b * T_STEPS + tp0) * 512 + d * 256 + (tid & 255);
    float* o1 = out1 + ((size_t)tp0 * BATCH + b) * 512 + d * 256 + (tid & 255);
    const int o0d = sgn * 512;
    const int o1d = sgn * (BATCH * 512);

    __syncthreads();

    for (int t = 0; t < T_STEPS; ++t) {
        // land this step's gx row in LDS; issue next step's load (stays in
        // flight across the lgkm-only barriers)
        if (pf) {
            *(uint4*)(gxb + pt * 8) = greg;
            if (t + 1 < T_STEPS) {
                gp += gpd;
                greg = *(const uint4*)gp;
            }
        }

        // ---- dot phase: 4 independent chains x 32 dot2 (K=256) ----
        float acc[4] = {Wb, 0.f, 0.f, 0.f};
#pragma unroll
        for (int c = 0; c < 4; ++c) {
            union { uint4 u; half2_t h[4]; } hv[8];
#pragma unroll
            for (int j = 0; j < 8; ++j)
                hv[j].u = *(const uint4*)(h16 + c * 64 + j * 8);   // broadcast
#pragma unroll
            for (int j = 0; j < 8; ++j)
#pragma unroll
                for (int p = 0; p < 4; ++p)
                    acc[c] = fdot2(Wr[c * 32 + j * 4 + p], hv[j].h[p], acc[c]);
        }
        gh[row] = (acc[0] + acc[1]) + (acc[2] + acc[3]);

        barrier_lgkm();

        // ---- gate phase (first 4 waves) ----
        if (tid < 256) {
            const int i = tid;
            float hr = gh[i];
            float hz = gh[256 + i];
            float hn = gh[512 + i];      // includes b_hn
            const _Float16* gxh = (const _Float16*)gxb;
            float xr = (float)gxh[i]       + hr;   // b_ih+b_hr in gx
            float xz = (float)gxh[256 + i] + hz;   // b_ih+b_hz in gx
            // sigmoid via exp2; saturates cleanly at +-inf (no NaN)
            float r = __builtin_amdgcn_rcpf(1.f + __builtin_amdgcn_exp2f(xr * -1.44269504f));
            float z = __builtin_amdgcn_rcpf(1.f + __builtin_amdgcn_exp2f(xz * -1.44269504f));
            float nx = (float)gxh[512 + i] + r * hn;
            float e2 = __builtin_amdgcn_exp2f(nx * 2.88539008f);
            float n  = 1.f - 2.f * __builtin_amdgcn_rcpf(1.f + e2);   // tanh
            float h  = n + z * (hprev - n);
            hprev = h;

            h16[i] = __builtin_bit_cast(ushort, (_Float16)h);
            *o0 = h; *o1 = h;
            o0 += o0d; o1 += o1d;
        }
        barrier_lgkm();
    }
}

// ---------------------------------------------------------------------------
extern "C" void kernel_launch(void* const* d_in, const int* in_sizes, int n_in,
                              void* d_out, int out_size, void* d_ws, size_t ws_size,
                              hipStream_t stream) {
    const float* x   = (const float*)d_in[0];
    const float* Wih = (const float*)d_in[1];
    const float* Whh = (const float*)d_in[2];
    const float* bih = (const float*)d_in[3];
    const float* bhh = (const float*)d_in[4];

    float* out0 = (float*)d_out;                          // outputs [32,2048,512]
    float* out1 = out0 + (size_t)BATCH * T_STEPS * 512;   // hiddens [2048,32,512]

    _Float16* gx = (_Float16*)d_ws;                       // 96MB

    gx_gemm<<<dim3(65536 / 64), dim3(256), 0, stream>>>(x, Wih, bih, bhh, gx);
    gru_seq<<<dim3(BATCH * 2), dim3(768), 0, stream>>>(gx, Whh, bhh, out0, out1);
}